// Round 3
// baseline (115.039 us; speedup 1.0000x reference)
//
#include <hip/hip_runtime.h>

// B=32, S=4096, C=64, D=2. x:[B,S,C,D] fp32, W_nonlin/W_coeff:[C,2,2] fp32.
// Per site: y = Wn @ x (2x2), amp = |y|^2, c = amp*y, z = Wc @ c.
// Memory-bound streaming: 64 MiB in + 64 MiB out.
//
// Ladder so far (kernel dispatch time):
//   grid-stride MLP~1:          ~34 us (3.9 TB/s)
//   batch-8, 8-MiB stride:       44 us (2.9 TB/s)  row-buffer thrash
//   batch-8, contiguous chunk:  ~30 us (4.2 TB/s)  <- round 2
// Copy ubench (same R/W mix) sustains 6.29 TB/s -> ~9 us of headroom left.
//
// Round-2 diagnosis: two-phase convoy. {8 loads}->{8 compute+store} leaves
// ZERO reads outstanding during each wave's store phase; waves are
// phase-synchronized machine-wide, so read queues drain between bursts.
// This version software-pipelines 4 batches of 4 with register double-
// buffering: batch b+1's loads are issued before batch b's compute+store,
// keeping a steady read+write mixture on the bus at all times.
//
// Layout stays block-contiguous: block b owns 4096 consecutive float4s
// (64 KiB read + 64 KiB written); thread t touches base + i*256, i=0..15.
// cp = t & 31 is offset-invariant (all offsets multiples of 32), so the
// four 2x2 weight matrices live in 16 registers.

constexpr int THREADS    = 256;
constexpr int BATCH      = 4;                      // float4 per thread per batch
constexpr int NBATCH     = 4;                      // batches per thread
constexpr int PER_THREAD = BATCH * NBATCH;         // 16
constexpr int CHUNK      = THREADS * PER_THREAD;   // 4096 float4 = 64 KiB

__device__ __forceinline__ float4 two_channels(const float4 v,
                                               const float4 wn0, const float4 wn1,
                                               const float4 wc0, const float4 wc1)
{
    float4 r;
    // channel 2cp: input (v.x, v.y)
    {
        float y0  = v.x * wn0.x + v.y * wn0.y;
        float y1  = v.x * wn0.z + v.y * wn0.w;
        float amp = y0 * y0 + y1 * y1;
        float c0  = amp * y0;
        float c1  = amp * y1;
        r.x = c0 * wc0.x + c1 * wc0.y;
        r.y = c0 * wc0.z + c1 * wc0.w;
    }
    // channel 2cp+1: input (v.z, v.w)
    {
        float y0  = v.z * wn1.x + v.w * wn1.y;
        float y1  = v.z * wn1.z + v.w * wn1.w;
        float amp = y0 * y0 + y1 * y1;
        float c0  = amp * y0;
        float c1  = amp * y1;
        r.z = c0 * wc1.x + c1 * wc1.y;
        r.w = c0 * wc1.z + c1 * wc1.w;
    }
    return r;
}

__global__ __launch_bounds__(THREADS) void fused_cplx_nonlin_pipe(
    const float4* __restrict__ x,
    const float4* __restrict__ Wn,   // [C,2,2] viewed as float4[C]
    const float4* __restrict__ Wc,
    float4* __restrict__ z)
{
    const int t    = threadIdx.x;
    const int base = blockIdx.x * CHUNK + t;
    const int cp   = t & 31;

    const float4 wn0 = Wn[2 * cp];
    const float4 wn1 = Wn[2 * cp + 1];
    const float4 wc0 = Wc[2 * cp];
    const float4 wc1 = Wc[2 * cp + 1];

    // Register double-buffer: two 4-deep batches. All loop indices are
    // compile-time constants after unrolling (no scratch spill, rule #20).
    float4 v[2][BATCH];

    // Prologue: batch 0 in flight.
#pragma unroll
    for (int j = 0; j < BATCH; ++j)
        v[0][j] = x[base + j * THREADS];

#pragma unroll
    for (int b = 0; b < NBATCH; ++b) {
        const int cur = b & 1;
        const int nxt = cur ^ 1;
        // Issue next batch's loads BEFORE consuming current batch:
        // steady state keeps 4-8 reads + up to 4 writes outstanding/lane.
        if (b + 1 < NBATCH) {
#pragma unroll
            for (int j = 0; j < BATCH; ++j)
                v[nxt][j] = x[base + ((b + 1) * BATCH + j) * THREADS];
        }
#pragma unroll
        for (int j = 0; j < BATCH; ++j)
            z[base + (b * BATCH + j) * THREADS] =
                two_channels(v[cur][j], wn0, wn1, wc0, wc1);
    }
}

// Generic fallback (grid-stride) for shapes that don't divide.
__global__ __launch_bounds__(THREADS) void fused_cplx_nonlin_generic(
    const float4* __restrict__ x,
    const float4* __restrict__ Wn,
    const float4* __restrict__ Wc,
    float4* __restrict__ z,
    int n4, int stride)
{
    const int g  = blockIdx.x * THREADS + threadIdx.x;
    const int cp = g & 31;

    const float4 wn0 = Wn[2 * cp];
    const float4 wn1 = Wn[2 * cp + 1];
    const float4 wc0 = Wc[2 * cp];
    const float4 wc1 = Wc[2 * cp + 1];

    for (int idx = g; idx < n4; idx += stride)
        z[idx] = two_channels(x[idx], wn0, wn1, wc0, wc1);
}

extern "C" void kernel_launch(void* const* d_in, const int* in_sizes, int n_in,
                              void* d_out, int out_size, void* d_ws, size_t ws_size,
                              hipStream_t stream) {
    const float4* x  = (const float4*)d_in[0];
    const float4* Wn = (const float4*)d_in[1];
    const float4* Wc = (const float4*)d_in[2];
    float4* z        = (float4*)d_out;

    const int n4 = in_sizes[0] / 4;              // 4,194,304 float4s

    if (n4 % CHUNK == 0) {
        // 4,194,304 / 4096 = 1024 blocks -> 4 blocks/CU, 16 waves/CU.
        const int blocks = n4 / CHUNK;
        fused_cplx_nonlin_pipe<<<blocks, THREADS, 0, stream>>>(x, Wn, Wc, z);
    } else {
        const int blocks = 2048;
        const int stride = blocks * THREADS;
        fused_cplx_nonlin_generic<<<blocks, THREADS, 0, stream>>>(
            x, Wn, Wc, z, n4, stride);
    }
}

// Round 6
// 113.218 us; speedup vs baseline: 1.0161x; 1.0161x over previous
//
#include <hip/hip_runtime.h>

// B=32, S=4096, C=64, D=2. x:[B,S,C,D] fp32, W_nonlin/W_coeff:[C,2,2] fp32.
// Per site: y = Wn @ x (2x2), amp = |y|^2, c = amp*y, z = Wc @ c.
// Memory-bound streaming: 64 MiB in + 64 MiB out.
//
// Ladder (kernel dispatch time, fills excluded):
//   grid-stride MLP~1:          ~34 us (3.9 TB/s)
//   batch-8, 8-MiB stride:       44 us (2.9 TB/s)  row-buffer thrash
//   batch-8, contiguous chunk:  ~30 us (4.2 TB/s)
//   + reg double-buffer pipe:   ~30 us  NEUTRAL -> not latency-bound
//   + nt stores:                r4 compile-fix; r5 core-dumped in harness
//                               teardown (suspected infra flake -- pytest ran
//                               full duration, no HIP error, no absmax).
//                               This round: controlled retry, code identical
//                               to r3 except the nt store instruction.
//
// Round-3 diagnosis: WRITE_SIZE = 93 MB vs 67 MB ideal (+39%) while FETCH
// is UNDER ideal (33 MB, x half L3-resident). The harness's 256-MiB poison
// fill leaves L3 fully dirty; z-writes allocate in L3, forcing dirty-poison
// evictions AND displacing x's resident lines. z is written once and never
// read -> nontemporal (nt) stores: no-pollute/evict-first. Loads stay
// normal (x's L3 hits are free bandwidth).
//
// Layout: block b owns 4096 consecutive float4s (64 KiB in + 64 KiB out);
// thread t touches base + i*256, i=0..15, as 4 pipelined batches of 4.
// cp = t & 31 is offset-invariant (offsets are multiples of 32), so the
// four 2x2 weight matrices live in 16 registers.

constexpr int THREADS    = 256;
constexpr int BATCH      = 4;                      // float4 per thread per batch
constexpr int NBATCH     = 4;                      // batches per thread
constexpr int PER_THREAD = BATCH * NBATCH;         // 16
constexpr int CHUNK      = THREADS * PER_THREAD;   // 4096 float4 = 64 KiB

// Native 4-float vector: same 16-B layout as HIP float4, but accepted by
// __builtin_nontemporal_store (HIP float4 is a class -> rejected).
typedef float nfloat4 __attribute__((ext_vector_type(4)));

__device__ __forceinline__ float4 two_channels(const float4 v,
                                               const float4 wn0, const float4 wn1,
                                               const float4 wc0, const float4 wc1)
{
    float4 r;
    // channel 2cp: input (v.x, v.y)
    {
        float y0  = v.x * wn0.x + v.y * wn0.y;
        float y1  = v.x * wn0.z + v.y * wn0.w;
        float amp = y0 * y0 + y1 * y1;
        float c0  = amp * y0;
        float c1  = amp * y1;
        r.x = c0 * wc0.x + c1 * wc0.y;
        r.y = c0 * wc0.z + c1 * wc0.w;
    }
    // channel 2cp+1: input (v.z, v.w)
    {
        float y0  = v.z * wn1.x + v.w * wn1.y;
        float y1  = v.z * wn1.z + v.w * wn1.w;
        float amp = y0 * y0 + y1 * y1;
        float c0  = amp * y0;
        float c1  = amp * y1;
        r.z = c0 * wc1.x + c1 * wc1.y;
        r.w = c0 * wc1.z + c1 * wc1.w;
    }
    return r;
}

__device__ __forceinline__ void nt_store4(float4* p, const float4 r)
{
    nfloat4 nv;
    nv.x = r.x; nv.y = r.y; nv.z = r.z; nv.w = r.w;
    __builtin_nontemporal_store(nv, reinterpret_cast<nfloat4*>(p));
}

__global__ __launch_bounds__(THREADS) void fused_cplx_nonlin_nt(
    const float4* __restrict__ x,
    const float4* __restrict__ Wn,   // [C,2,2] viewed as float4[C]
    const float4* __restrict__ Wc,
    float4* __restrict__ z)
{
    const int t    = threadIdx.x;
    const int base = blockIdx.x * CHUNK + t;
    const int cp   = t & 31;

    const float4 wn0 = Wn[2 * cp];
    const float4 wn1 = Wn[2 * cp + 1];
    const float4 wc0 = Wc[2 * cp];
    const float4 wc1 = Wc[2 * cp + 1];

    // Register double-buffer: two 4-deep batches; all indices compile-time
    // constant after unrolling (no scratch, rule #20).
    float4 v[2][BATCH];

#pragma unroll
    for (int j = 0; j < BATCH; ++j)
        v[0][j] = x[base + j * THREADS];

#pragma unroll
    for (int b = 0; b < NBATCH; ++b) {
        const int cur = b & 1;
        const int nxt = cur ^ 1;
        if (b + 1 < NBATCH) {
#pragma unroll
            for (int j = 0; j < BATCH; ++j)
                v[nxt][j] = x[base + ((b + 1) * BATCH + j) * THREADS];
        }
#pragma unroll
        for (int j = 0; j < BATCH; ++j) {
            const float4 r = two_channels(v[cur][j], wn0, wn1, wc0, wc1);
            // z written once, never read: nt store -> no L2/L3 pollution,
            // no dirty-poison eviction churn, x's L3 lines stay resident.
            nt_store4(&z[base + (b * BATCH + j) * THREADS], r);
        }
    }
}

// Generic fallback (grid-stride, plain stores) for shapes that don't divide.
__global__ __launch_bounds__(THREADS) void fused_cplx_nonlin_generic(
    const float4* __restrict__ x,
    const float4* __restrict__ Wn,
    const float4* __restrict__ Wc,
    float4* __restrict__ z,
    int n4, int stride)
{
    const int g  = blockIdx.x * THREADS + threadIdx.x;
    const int cp = g & 31;

    const float4 wn0 = Wn[2 * cp];
    const float4 wn1 = Wn[2 * cp + 1];
    const float4 wc0 = Wc[2 * cp];
    const float4 wc1 = Wc[2 * cp + 1];

    for (int idx = g; idx < n4; idx += stride)
        z[idx] = two_channels(x[idx], wn0, wn1, wc0, wc1);
}

extern "C" void kernel_launch(void* const* d_in, const int* in_sizes, int n_in,
                              void* d_out, int out_size, void* d_ws, size_t ws_size,
                              hipStream_t stream) {
    const float4* x  = (const float4*)d_in[0];
    const float4* Wn = (const float4*)d_in[1];
    const float4* Wc = (const float4*)d_in[2];
    float4* z        = (float4*)d_out;

    const int n4 = in_sizes[0] / 4;              // 4,194,304 float4s

    if (n4 % CHUNK == 0) {
        // 4,194,304 / 4096 = 1024 blocks -> 4 blocks/CU, 16 waves/CU.
        const int blocks = n4 / CHUNK;
        fused_cplx_nonlin_nt<<<blocks, THREADS, 0, stream>>>(x, Wn, Wc, z);
    } else {
        const int blocks = 2048;
        const int stride = blocks * THREADS;
        fused_cplx_nonlin_generic<<<blocks, THREADS, 0, stream>>>(
            x, Wn, Wc, z, n4, stride);
    }
}